// Round 1
// baseline (79.214 us; speedup 1.0000x reference)
//
#include <hip/hip_runtime.h>

// Shape fixed by reference setup_inputs(): B=256, L=512, D=64, fp32.
constexpr int Bn = 256;
constexpr int Ln = 512;
constexpr int Dn = 64;
constexpr float EPS_LOG = 1e-7f;
constexpr float EPS_COS = 1e-8f;

// Reference only consumes wnl[b,b], so per sample we need one cosine row:
// cos(emb[b,b,:], emb[b,k,:]) for k in [0,512).
//
// R1 (this round): split each sample across 4 blocks instead of 1.
//   grid = 1024 blocks x 512 threads (8 waves). Block (b,q) handles rows
//   [q*128, q*128+128) -> 4 blocks/CU, 32 waves/CU. This overlaps one
//   block's serial prologue/epilogue with another block's streaming loads
//   (previous version had exactly 1 block/CU = zero inter-block overlap).
//
// Bit-exactness discipline (prev version scored absmax 0.0 — preserve it):
//  * prob-phase: only q==0 blocks, 512 threads, wave w owns elements
//    [w*64, w*64+64) — IDENTICAL lane->element mapping and the same
//    sequential wave-partial sum order as before (old waves 8..15
//    contributed exact +0.f, dropping them is exact).
//  * max: fmax is order-exact for the relu'd (>=0) values; per-quarter
//    gating g_q = (lb[b,b]==0 ? max_q : 0) then max over q in K2 equals
//    the old gate-after-full-max since all partials are >= 0.
//  * K2 computes r_b = -P - wnl*LN with the same expression and sums
//    samples in the same order (4 sequential per lane, then 6-step xor
//    tree, then * (1/256)).
//
// ws layout (1536 floats, 6 KB):
//   ws[4b+q]    : gated per-quarter row-max partial
//   ws[1024+b]  : P   (sum labels*log(p+eps)),  written by q==0 block
//   ws[1280+b]  : LN  (sum log(1-(p+eps))),     written by q==0 block
// Poisoned d_ws/d_out are never read before being overwritten.

constexpr int QUARTERS = 4;                    // blocks per sample
constexpr int ROWS_PER_BLK = Ln / QUARTERS;    // 128
constexpr int NW = 8;                          // waves per block

__global__ __launch_bounds__(512) void wnl_part(
    const float* __restrict__ emb,     // (B, L, D)
    const float* __restrict__ probs,   // (B, L)
    const float* __restrict__ labels,  // (B, L)
    float* __restrict__ ws)
{
    const int blk  = blockIdx.x;
    const int b    = blk >> 2;         // sample
    const int q    = blk & 3;          // row-quarter
    const int tid  = threadIdx.x;
    const int wave = tid >> 6;         // 0..7
    const int lane = tid & 63;
    const int sub  = lane >> 4;        // row within the wave's 4-row group
    const int i16  = lane & 15;        // float4 chunk of D

    const float* eb = emb    + (size_t)b * Ln * Dn;
    const float* pb = probs  + (size_t)b * Ln;
    const float* lb = labels + (size_t)b * Ln;

    // q-row = emb[b,b,:]; 16 B/lane, broadcast across subgroups (L1-hit).
    const float4 qv = *(const float4*)(eb + (size_t)b * Dn + 4 * i16);
    float nq = qv.x * qv.x + qv.y * qv.y + qv.z * qv.z + qv.w * qv.w;
    #pragma unroll
    for (int off = 1; off < 16; off <<= 1) nq += __shfl_xor(nq, off);
    const float norm_q = sqrtf(nq);

    // 128 rows / (8 waves * 4 rows) = 4 fully-unrolled independent iters;
    // each wave's 4 subgroups cover 4 consecutive rows = 1 KB burst.
    float maxv = 0.f;
    #pragma unroll
    for (int it = 0; it < ROWS_PER_BLK / (NW * 4); ++it) {
        const int k = q * ROWS_PER_BLK + it * (NW * 4) + wave * 4 + sub;
        const float4 v = *(const float4*)(eb + (size_t)k * Dn + 4 * i16);
        const float lk = lb[k];
        float d = qv.x * v.x + qv.y * v.y + qv.z * v.z + qv.w * v.w;
        float n = v.x * v.x + v.y * v.y + v.z * v.z + v.w * v.w;
        #pragma unroll
        for (int off = 1; off < 16; off <<= 1) {
            d += __shfl_xor(d, off);
            n += __shfl_xor(n, off);
        }
        float denom = fmaxf(norm_q * sqrtf(n), EPS_COS);
        float m     = fmaxf(__fdividef(d, denom), 0.f) * lk;  // relu, mask
        maxv = fmaxf(maxv, m);
    }
    maxv = fmaxf(maxv, __shfl_xor(maxv, 16));
    maxv = fmaxf(maxv, __shfl_xor(maxv, 32));

    // prob sums (q==0 blocks only; all 8 waves active, same element
    // mapping as the previous version: element index == tid).
    float pos = 0.f, lng = 0.f;
    if (q == 0) {
        float p = pb[tid] + EPS_LOG;
        pos = lb[tid] * __logf(p);
        lng = __logf(1.f - p);
        #pragma unroll
        for (int off = 32; off; off >>= 1) {
            pos += __shfl_xor(pos, off);
            lng += __shfl_xor(lng, off);
        }
    }

    __shared__ float s_max[NW], s_pos[NW], s_lng[NW];
    if (lane == 0) { s_max[wave] = maxv; s_pos[wave] = pos; s_lng[wave] = lng; }
    __syncthreads();

    if (tid == 0) {
        float rm = 0.f;
        #pragma unroll
        for (int w = 0; w < NW; ++w) rm = fmaxf(rm, s_max[w]);
        // gate on labels[b,b]: quarter-maxes are >= 0, so gating each
        // partial then maxing in K2 == gating the full max (exact).
        ws[4 * b + q] = (lb[b] == 0.f) ? rm : 0.f;
        if (q == 0) {
            float P = 0.f, LN = 0.f;
            #pragma unroll
            for (int w = 0; w < NW; ++w) { P += s_pos[w]; LN += s_lng[w]; }
            ws[1024 + b] = P;
            ws[1280 + b] = LN;
        }
    }
}

// K2: one wave combines the 4 quarter-maxes per sample, forms
// r_b = -P - wnl*LN, and sums the 256 samples (same order as before:
// 4 sequential samples per lane, 6-step xor tree, * 1/256).
__global__ __launch_bounds__(64) void wnl_final(
    const float* __restrict__ ws,
    float* __restrict__ out)
{
    const int lane = threadIdx.x;                // 0..63
    const float4 m0 = ((const float4*)ws)[4 * lane + 0];  // sample 4l+0
    const float4 m1 = ((const float4*)ws)[4 * lane + 1];  // sample 4l+1
    const float4 m2 = ((const float4*)ws)[4 * lane + 2];  // sample 4l+2
    const float4 m3 = ((const float4*)ws)[4 * lane + 3];  // sample 4l+3
    const float4 P  = ((const float4*)(ws + 1024))[lane];
    const float4 L  = ((const float4*)(ws + 1280))[lane];

    const float w0 = fmaxf(fmaxf(m0.x, m0.y), fmaxf(m0.z, m0.w));
    const float w1 = fmaxf(fmaxf(m1.x, m1.y), fmaxf(m1.z, m1.w));
    const float w2 = fmaxf(fmaxf(m2.x, m2.y), fmaxf(m2.z, m2.w));
    const float w3 = fmaxf(fmaxf(m3.x, m3.y), fmaxf(m3.z, m3.w));

    const float r0 = -P.x - w0 * L.x;
    const float r1 = -P.y - w1 * L.y;
    const float r2 = -P.z - w2 * L.z;
    const float r3 = -P.w - w3 * L.w;

    float t = r0 + r1 + r2 + r3;
    #pragma unroll
    for (int off = 32; off; off >>= 1) t += __shfl_xor(t, off);
    if (lane == 0) out[0] = t * (1.f / (float)Bn);
}

extern "C" void kernel_launch(void* const* d_in, const int* in_sizes, int n_in,
                              void* d_out, int out_size, void* d_ws, size_t ws_size,
                              hipStream_t stream) {
    const float* emb    = (const float*)d_in[0];
    const float* probs  = (const float*)d_in[1];
    const float* labels = (const float*)d_in[2];
    float* ws  = (float*)d_ws;
    float* out = (float*)d_out;

    wnl_part<<<Bn * QUARTERS, 512, 0, stream>>>(emb, probs, labels, ws);
    wnl_final<<<1, 64, 0, stream>>>(ws, out);
}